// Round 11
// baseline (521.419 us; speedup 1.0000x reference)
//
#include <hip/hip_runtime.h>

#define JITTER 1e-5f

__device__ __forceinline__ float fast_rcp(float v) {
#if __has_builtin(__builtin_amdgcn_rcpf)
    return __builtin_amdgcn_rcpf(v);
#else
    return 1.0f / v;
#endif
}
// broadcast lane k's value to all lanes via DS-pipe (VGPR dest, no SGPR hazard)
__device__ __forceinline__ float bp(float v, int k) {
    return __int_as_float(__builtin_amdgcn_ds_bpermute(k * 4, __float_as_int(v)));
}

// ---------------------------------------------------------------------------
// One kernel, 256 blocks x 512 threads (2 particles/block). Round-7 verified
// structure and recurrence (absmax 4.9e-4, twice verified). Change vs r7:
// every readlane broadcast -> ds_bpermute (VGPR-dest, pipelined in the DS
// queue), batched 16-at-a-time so the ~60cy LDS latency is paid per batch,
// not per pair (r7/r9 measured ~29 cyc/readlane+fma pair). The matrix build
// reads z_c rows as UNIFORM ds_read_b128 (broadcast = free) from a row-major
// LDS copy instead of 512 readlane pairs. Peak VGPR ~100 (row64+s16+misc):
// no spill, 2 blocks/CU kept. All register indices compile-time static.
// ---------------------------------------------------------------------------
__global__ __launch_bounds__(512) void diag_sgp_fused5(
    const float* __restrict__ x,        // (n,8)
    const float* __restrict__ y,        // (n,32)
    const float* __restrict__ z,        // (n,2048)
    const float* __restrict__ gamma,    // (n,2048)
    const float* __restrict__ inducing, // (64,8)
    const float* __restrict__ Kmat,     // (32,32)
    const float* __restrict__ pvar,
    const float* __restrict__ pls,
    const float* __restrict__ pnoise,
    float* __restrict__ out,            // [m_new (n,2048) | g (n,2048)]
    int n_total)
{
    const int tid = threadIdx.x;
    const int n0  = blockIdx.x * 2;
    const int t8  = tid & 255;           // thread within particle
    const int h   = tid >> 8;            // particle half (0/1)

    // ---- prefetch HBM-heavy operands immediately ----
    const size_t base = (size_t)(n0 + h) * 2048 + t8 * 8;
    const float4 g0 = *reinterpret_cast<const float4*>(gamma + base);
    const float4 g1 = *reinterpret_cast<const float4*>(gamma + base + 4);
    const float4 zv0 = *reinterpret_cast<const float4*>(z + base);
    const float4 zv1 = *reinterpret_cast<const float4*>(z + base + 4);

    __shared__ __align__(16) float Zl[64 * 8];     // inducing, row-major
    __shared__ float Kl[32 * 33];                  // K, pitch 33
    __shared__ float xl[2][8], yl[2][32];
    __shared__ float e_sh[2][64];
    __shared__ __align__(16) float a_sh[2][64];
    __shared__ float t_sh[2][32], rc[2][32], rd[2][32], s1s[2][32], s2s[2][32];
    __shared__ float Bsh[2];

    Zl[tid & 511] = inducing[tid & 511];           // 512 threads: direct copy
    for (int i = tid; i < 1024; i += 512)
        Kl[(i >> 5) * 33 + (i & 31)] = Kmat[i];
    if (tid < 16) xl[tid >> 3][tid & 7]  = x[n0 * 8 + tid];
    if (tid < 64) yl[tid >> 5][tid & 31] = y[n0 * 32 + tid];
    const float var = pvar[0], ls = pls[0], nv = pnoise[0];
    const float sc = 0.5f / (ls * ls);
    __syncthreads();                               // B1

    // ================= wave-0 register GJ solve (row-per-lane) ===========
    if (tid < 64) {
        const int lane = tid;
        float zc[8];
        {   // own z-row from global, coalesced float4 x2
            const float4 za = *reinterpret_cast<const float4*>(inducing + lane * 8);
            const float4 zb = *reinterpret_cast<const float4*>(inducing + lane * 8 + 4);
            zc[0] = za.x; zc[1] = za.y; zc[2] = za.z; zc[3] = za.w;
            zc[4] = zb.x; zc[5] = zb.y; zc[6] = zb.z; zc[7] = zb.w;
        }

        // build rows: row[c] = M[lane][c]; z_c rows via UNIFORM b128 reads
        float row[64];
#pragma unroll
        for (int cb = 0; cb < 64; cb += 4) {
            float zt[4][8];
#pragma unroll
            for (int u = 0; u < 4; ++u) {
                const float4 r0 = *reinterpret_cast<const float4*>(&Zl[(cb + u) * 8]);
                const float4 r1 = *reinterpret_cast<const float4*>(&Zl[(cb + u) * 8 + 4]);
                zt[u][0] = r0.x; zt[u][1] = r0.y; zt[u][2] = r0.z; zt[u][3] = r0.w;
                zt[u][4] = r1.x; zt[u][5] = r1.y; zt[u][6] = r1.z; zt[u][7] = r1.w;
            }
            __builtin_amdgcn_sched_barrier(0);
#pragma unroll
            for (int u = 0; u < 4; ++u) {
                const int c = cb + u;
                float sq = 0.f;
#pragma unroll
                for (int dd = 0; dd < 8; ++dd) {
                    const float df = zc[dd] - zt[u][dd];
                    sq = fmaf(df, df, sq);
                }
                const float v = __expf(-sq * sc);
                row[c] = (lane == c) ? v + JITTER : v;
            }
        }
        // RHS (lane-local), both particles
        float b0, b1;
        {
            float sq0 = 0.f, sq1 = 0.f;
#pragma unroll
            for (int dd = 0; dd < 8; ++dd) {
                const float d0 = xl[0][dd] - zc[dd]; sq0 = fmaf(d0, d0, sq0);
                const float d1 = xl[1][dd] - zc[dd]; sq1 = fmaf(d1, d1, sq1);
            }
            b0 = __expf(-sq0 * sc);
            b1 = __expf(-sq1 * sc);
        }
        e_sh[0][lane] = b0;
        e_sh[1][lane] = b1;

        // ---- elimination: identical factors/order to r7; bpermute bcast ----
        float dg = 1.f;
#pragma unroll
        for (int k = 0; k < 64; ++k) {
            const float piv  = bp(row[k], k);      // M[k][k] broadcast
            const float rinv = fast_rcp(piv);
            const float fr   = (lane == k) ? 0.f : row[k] * rinv;
            float bk0, bk1;

#define ELIM_CHUNK(LO)                                                        \
            if (k + (LO) < 64) {                                              \
                float s[16];                                                  \
                _Pragma("unroll")                                             \
                for (int c = 0; c < 64; ++c)                                  \
                    if (c >= k + (LO) && c < k + (LO) + 16)                   \
                        s[c - k - (LO)] = bp(row[c], k);                      \
                if ((LO) == 0) { bk0 = bp(b0, k); bk1 = bp(b1, k); }          \
                __builtin_amdgcn_sched_barrier(0);                            \
                _Pragma("unroll")                                             \
                for (int c = 0; c < 64; ++c)                                  \
                    if (c >= k + (LO) && c < k + (LO) + 16)                   \
                        row[c] = fmaf(-fr, s[c - k - (LO)], row[c]);          \
            }

            ELIM_CHUNK(0)
            ELIM_CHUNK(16)
            ELIM_CHUNK(32)
            ELIM_CHUNK(48)
#undef ELIM_CHUNK

            b0 = fmaf(-fr, bk0, b0);
            b1 = fmaf(-fr, bk1, b1);
            dg = (lane == k) ? piv : dg;
        }
        a_sh[0][lane] = b0 / dg;
        a_sh[1][lane] = b1 / dg;
    }
    __syncthreads();                               // B2

    // ================= verified epilogue, 2 particles =================
    if (t8 < 64) {                                 // waves 0 & 4: B reduce
        float v = e_sh[h][t8] * a_sh[h][t8];
        for (int off = 32; off; off >>= 1) v += __shfl_down(v, off);
        if (t8 == 0) Bsh[h] = var * (1.f - v);
    }

    // t[j] partials via 8-lane shfl tree
    const int jrow = t8 >> 3;
    float ga[8] = {g0.x, g0.y, g0.z, g0.w, g1.x, g1.y, g1.z, g1.w};
    const int ab = (t8 & 7) * 8;
    const float4 a0 = *reinterpret_cast<const float4*>(&a_sh[h][ab]);
    const float4 a1 = *reinterpret_cast<const float4*>(&a_sh[h][ab + 4]);
    const float as[8] = {a0.x, a0.y, a0.z, a0.w, a1.x, a1.y, a1.z, a1.w};

    float pt = 0.f;
#pragma unroll
    for (int e = 0; e < 8; ++e) pt += as[e] * as[e] * ga[e];
    pt += __shfl_xor(pt, 1);
    pt += __shfl_xor(pt, 2);
    pt += __shfl_xor(pt, 4);
    if ((t8 & 7) == 0) t_sh[h][jrow] = pt;
    __syncthreads();                               // B3

    if (t8 < 32) {                                 // c, d per output dim
        float acc = 0.f;
        for (int jj = 0; jj < 32; ++jj) {
            const float kv = Kl[t8 * 33 + jj];
            acc += kv * kv * t_sh[h][jj];
        }
        const float ci = Bsh[h] * Kl[t8 * 34] + nv;
        const float di = acc + ci;
        rc[h][t8] = yl[h][t8] / ci;
        rd[h][t8] = 1.0f / di;
    }
    __syncthreads();                               // B4

    if (t8 < 32) {                                 // s1, s2 per j
        float sa = 0.f, sb = 0.f;
        for (int i = 0; i < 32; ++i) {
            const float kv = Kl[i * 33 + t8];
            sa += kv * rc[h][i];
            sb += kv * kv * rd[h][i];
        }
        s1s[h][t8] = sa;
        s2s[h][t8] = sb;
    }
    __syncthreads();                               // B5

    const float zv[8] = {zv0.x, zv0.y, zv0.z, zv0.w, zv1.x, zv1.y, zv1.z, zv1.w};
    const float s1j = s1s[h][jrow], s2j = s2s[h][jrow];
    float mn[8], gg[8];
#pragma unroll
    for (int e = 0; e < 8; ++e) {
        const float ge = ga[e];
        const float am = as[e];
        const float gm = ge * am;
        const float gv = ge - gm * gm * s2j;
        gg[e] = gv;
        mn[e] = gv * (zv[e] / ge + am * s1j);
    }

    float* o_m = out + base;
    float* o_g = out + (size_t)n_total * 2048 + base;
    *reinterpret_cast<float4*>(o_m)     = make_float4(mn[0], mn[1], mn[2], mn[3]);
    *reinterpret_cast<float4*>(o_m + 4) = make_float4(mn[4], mn[5], mn[6], mn[7]);
    *reinterpret_cast<float4*>(o_g)     = make_float4(gg[0], gg[1], gg[2], gg[3]);
    *reinterpret_cast<float4*>(o_g + 4) = make_float4(gg[4], gg[5], gg[6], gg[7]);
}

extern "C" void kernel_launch(void* const* d_in, const int* in_sizes, int n_in,
                              void* d_out, int out_size, void* d_ws, size_t ws_size,
                              hipStream_t stream)
{
    const float* x        = (const float*)d_in[0];
    const float* y        = (const float*)d_in[1];
    const float* z        = (const float*)d_in[2];
    const float* gamma    = (const float*)d_in[3];
    const float* inducing = (const float*)d_in[4];
    const float* Kmat     = (const float*)d_in[5];
    const float* pvar     = (const float*)d_in[6];
    const float* pls      = (const float*)d_in[7];
    const float* pnoise   = (const float*)d_in[8];
    float* out = (float*)d_out;

    const int n = in_sizes[0] / 8;       // 512
    diag_sgp_fused5<<<dim3(n / 2), dim3(512), 0, stream>>>(
        x, y, z, gamma, inducing, Kmat, pvar, pls, pnoise, out, n);
}

// Round 13
// 27.626 us; speedup vs baseline: 18.8743x; 18.8743x over previous
//
#include <hip/hip_runtime.h>

#define JITTER 1e-5f

__device__ __forceinline__ float fast_rcp(float v) {
#if __has_builtin(__builtin_amdgcn_rcpf)
    return __builtin_amdgcn_rcpf(v);
#else
    return 1.0f / v;
#endif
}
// broadcast lane k's value to all 64 lanes via DS pipe (VGPR dest, defined
// cross-lane semantics -- no SGPR hazard, no memory-model race)
__device__ __forceinline__ float bp(float v, int k) {
    return __int_as_float(__builtin_amdgcn_ds_bpermute(k * 4, __float_as_int(v)));
}

// ---------------------------------------------------------------------------
// One kernel, 256 blocks x 512 threads (2 particles/block). Round-7 verified
// structure, recurrence, and epilogue (absmax 4.9e-4, twice verified).
// Single change vs r7: the broadcast primitive in the row-per-lane register
// Gauss-Jordan -- v_readlane (SGPR dest; measured ~29 cyc per pair from the
// serial VALU->SGPR->VALU stall) becomes ds_bpermute (VGPR dest, DS-pipe,
// pipelines under lgkmcnt). NO temp arrays, NO sched_barriers (the r10/r11
// spill-makers): register pressure stays at r7's proven-clean level and
// LLVM schedules the independent bpermutes itself.
// Matrix build: race-free uniform ds_read_b128 of the LDS Z copy (reads are
// after __syncthreads B1) -- broadcast reads are conflict-free.
// ---------------------------------------------------------------------------
__global__ __launch_bounds__(512) void diag_sgp_fused7(
    const float* __restrict__ x,        // (n,8)
    const float* __restrict__ y,        // (n,32)
    const float* __restrict__ z,        // (n,2048)
    const float* __restrict__ gamma,    // (n,2048)
    const float* __restrict__ inducing, // (64,8)
    const float* __restrict__ Kmat,     // (32,32)
    const float* __restrict__ pvar,
    const float* __restrict__ pls,
    const float* __restrict__ pnoise,
    float* __restrict__ out,            // [m_new (n,2048) | g (n,2048)]
    int n_total)
{
    const int tid = threadIdx.x;
    const int n0  = blockIdx.x * 2;
    const int t8  = tid & 255;           // thread within particle
    const int h   = tid >> 8;            // particle half (0/1)

    // ---- prefetch HBM-heavy operands immediately ----
    const size_t base = (size_t)(n0 + h) * 2048 + t8 * 8;
    const float4 g0 = *reinterpret_cast<const float4*>(gamma + base);
    const float4 g1 = *reinterpret_cast<const float4*>(gamma + base + 4);
    const float4 zv0 = *reinterpret_cast<const float4*>(z + base);
    const float4 zv1 = *reinterpret_cast<const float4*>(z + base + 4);

    __shared__ __align__(16) float Zl[64 * 8];     // inducing, row-major
    __shared__ float Kl[32 * 33];                  // K, pitch 33
    __shared__ float xl[2][8], yl[2][32];
    __shared__ float e_sh[2][64];
    __shared__ __align__(16) float a_sh[2][64];
    __shared__ float t_sh[2][32], rc[2][32], rd[2][32], s1s[2][32], s2s[2][32];
    __shared__ float Bsh[2];

    Zl[tid & 511] = inducing[tid & 511];           // 512 threads: direct copy
    for (int i = tid; i < 1024; i += 512)
        Kl[(i >> 5) * 33 + (i & 31)] = Kmat[i];
    if (tid < 16) xl[tid >> 3][tid & 7]  = x[n0 * 8 + tid];
    if (tid < 64) yl[tid >> 5][tid & 31] = y[n0 * 32 + tid];
    const float var = pvar[0], ls = pls[0], nv = pnoise[0];
    const float sc = 0.5f / (ls * ls);
    __syncthreads();                               // B1

    // ================= wave-0 register GJ solve (row-per-lane) ===========
    if (tid < 64) {
        const int lane = tid;
        float zc[8];
        {   // own z-row, coalesced global float4 x2
            const float4 za = *reinterpret_cast<const float4*>(inducing + lane * 8);
            const float4 zb = *reinterpret_cast<const float4*>(inducing + lane * 8 + 4);
            zc[0] = za.x; zc[1] = za.y; zc[2] = za.z; zc[3] = za.w;
            zc[4] = zb.x; zc[5] = zb.y; zc[6] = zb.z; zc[7] = zb.w;
        }

        // build rows: row[c] = M[lane][c]; z_c rows via UNIFORM b128 reads
        // (race-free: Zl written before __syncthreads B1)
        float row[64];
#pragma unroll
        for (int c = 0; c < 64; ++c) {
            const float4 r0 = *reinterpret_cast<const float4*>(&Zl[c * 8]);
            const float4 r1 = *reinterpret_cast<const float4*>(&Zl[c * 8 + 4]);
            float sq;
            {
                const float d0 = zc[0] - r0.x; sq  = d0 * d0;
                const float d1 = zc[1] - r0.y; sq = fmaf(d1, d1, sq);
                const float d2 = zc[2] - r0.z; sq = fmaf(d2, d2, sq);
                const float d3 = zc[3] - r0.w; sq = fmaf(d3, d3, sq);
                const float d4 = zc[4] - r1.x; sq = fmaf(d4, d4, sq);
                const float d5 = zc[5] - r1.y; sq = fmaf(d5, d5, sq);
                const float d6 = zc[6] - r1.z; sq = fmaf(d6, d6, sq);
                const float d7 = zc[7] - r1.w; sq = fmaf(d7, d7, sq);
            }
            const float v = __expf(-sq * sc);
            row[c] = (lane == c) ? v + JITTER : v;
        }
        // RHS (lane-local), both particles
        float b0, b1;
        {
            float sq0 = 0.f, sq1 = 0.f;
#pragma unroll
            for (int dd = 0; dd < 8; ++dd) {
                const float d0 = xl[0][dd] - zc[dd]; sq0 = fmaf(d0, d0, sq0);
                const float d1 = xl[1][dd] - zc[dd]; sq1 = fmaf(d1, d1, sq1);
            }
            b0 = __expf(-sq0 * sc);
            b1 = __expf(-sq1 * sc);
        }
        e_sh[0][lane] = b0;
        e_sh[1][lane] = b1;

        // ---- elimination: r7's exact recurrence, bpermute broadcasts ----
        float dg = 1.f;
#pragma unroll
        for (int k = 0; k < 64; ++k) {
            const float piv  = bp(row[k], k);      // M[k][k] broadcast
            const float rinv = fast_rcp(piv);
            const float fr   = (lane == k) ? 0.f : row[k] * rinv;
#pragma unroll
            for (int c = k; c < 64; ++c) {         // cols < k already zero
                const float s_c = bp(row[c], k);   // pivot row entry (VGPR)
                row[c] = fmaf(-fr, s_c, row[c]);
            }
            const float bk0 = bp(b0, k);
            const float bk1 = bp(b1, k);
            b0 = fmaf(-fr, bk0, b0);
            b1 = fmaf(-fr, bk1, b1);
            dg = (lane == k) ? piv : dg;
        }
        a_sh[0][lane] = b0 / dg;
        a_sh[1][lane] = b1 / dg;
    }
    __syncthreads();                               // B2

    // ================= verified epilogue, 2 particles =================
    if (t8 < 64) {                                 // waves 0 & 4: B reduce
        float v = e_sh[h][t8] * a_sh[h][t8];
        for (int off = 32; off; off >>= 1) v += __shfl_down(v, off);
        if (t8 == 0) Bsh[h] = var * (1.f - v);
    }

    // t[j] partials via 8-lane shfl tree
    const int jrow = t8 >> 3;
    float ga[8] = {g0.x, g0.y, g0.z, g0.w, g1.x, g1.y, g1.z, g1.w};
    const int ab = (t8 & 7) * 8;
    const float4 a0 = *reinterpret_cast<const float4*>(&a_sh[h][ab]);
    const float4 a1 = *reinterpret_cast<const float4*>(&a_sh[h][ab + 4]);
    const float as[8] = {a0.x, a0.y, a0.z, a0.w, a1.x, a1.y, a1.z, a1.w};

    float pt = 0.f;
#pragma unroll
    for (int e = 0; e < 8; ++e) pt += as[e] * as[e] * ga[e];
    pt += __shfl_xor(pt, 1);
    pt += __shfl_xor(pt, 2);
    pt += __shfl_xor(pt, 4);
    if ((t8 & 7) == 0) t_sh[h][jrow] = pt;
    __syncthreads();                               // B3

    if (t8 < 32) {                                 // c, d per output dim
        float acc = 0.f;
        for (int jj = 0; jj < 32; ++jj) {
            const float kv = Kl[t8 * 33 + jj];
            acc += kv * kv * t_sh[h][jj];
        }
        const float ci = Bsh[h] * Kl[t8 * 34] + nv;
        const float di = acc + ci;
        rc[h][t8] = yl[h][t8] / ci;
        rd[h][t8] = 1.0f / di;
    }
    __syncthreads();                               // B4

    if (t8 < 32) {                                 // s1, s2 per j
        float sa = 0.f, sb = 0.f;
        for (int i = 0; i < 32; ++i) {
            const float kv = Kl[i * 33 + t8];
            sa += kv * rc[h][i];
            sb += kv * kv * rd[h][i];
        }
        s1s[h][t8] = sa;
        s2s[h][t8] = sb;
    }
    __syncthreads();                               // B5

    const float zv[8] = {zv0.x, zv0.y, zv0.z, zv0.w, zv1.x, zv1.y, zv1.z, zv1.w};
    const float s1j = s1s[h][jrow], s2j = s2s[h][jrow];
    float mn[8], gg[8];
#pragma unroll
    for (int e = 0; e < 8; ++e) {
        const float ge = ga[e];
        const float am = as[e];
        const float gm = ge * am;
        const float gv = ge - gm * gm * s2j;
        gg[e] = gv;
        mn[e] = gv * (zv[e] / ge + am * s1j);
    }

    float* o_m = out + base;
    float* o_g = out + (size_t)n_total * 2048 + base;
    *reinterpret_cast<float4*>(o_m)     = make_float4(mn[0], mn[1], mn[2], mn[3]);
    *reinterpret_cast<float4*>(o_m + 4) = make_float4(mn[4], mn[5], mn[6], mn[7]);
    *reinterpret_cast<float4*>(o_g)     = make_float4(gg[0], gg[1], gg[2], gg[3]);
    *reinterpret_cast<float4*>(o_g + 4) = make_float4(gg[4], gg[5], gg[6], gg[7]);
}

extern "C" void kernel_launch(void* const* d_in, const int* in_sizes, int n_in,
                              void* d_out, int out_size, void* d_ws, size_t ws_size,
                              hipStream_t stream)
{
    const float* x        = (const float*)d_in[0];
    const float* y        = (const float*)d_in[1];
    const float* z        = (const float*)d_in[2];
    const float* gamma    = (const float*)d_in[3];
    const float* inducing = (const float*)d_in[4];
    const float* Kmat     = (const float*)d_in[5];
    const float* pvar     = (const float*)d_in[6];
    const float* pls      = (const float*)d_in[7];
    const float* pnoise   = (const float*)d_in[8];
    float* out = (float*)d_out;

    const int n = in_sizes[0] / 8;       // 512
    diag_sgp_fused7<<<dim3(n / 2), dim3(512), 0, stream>>>(
        x, y, z, gamma, inducing, Kmat, pvar, pls, pnoise, out, n);
}